// Round 9
// baseline (247.265 us; speedup 1.0000x reference)
//
#include <hip/hip_runtime.h>
#include <hip/hip_bf16.h>
#include <cstdint>
#include <cstddef>

// Problem constants: B=1, L=4096, DM=1024, NH=16, DH=64, w=512, C=8
#define L_ 4096
#define DM_ 1024
#define NH_ 16
#define DH_ 64
#define W_ 512
#define C_ 8
#define W3_ 1536
#define NROWS_ 65536

typedef __attribute__((ext_vector_type(8))) short short8;
typedef __attribute__((ext_vector_type(4))) float f32x4;

__device__ __forceinline__ void async16(const void* g, void* l) {
    __builtin_amdgcn_global_load_lds(
        (const __attribute__((address_space(1))) unsigned int*)g,
        (__attribute__((address_space(3))) unsigned int*)l, 16, 0, 0);
}

#if __has_builtin(__builtin_amdgcn_exp2f)
#define FEXP2(x) __builtin_amdgcn_exp2f(x)
#else
#define FEXP2(x) exp2f(x)
#endif

// ---------------------------------------------------------------------------
// Input-dtype detector (fp32 vs bf16).
// ---------------------------------------------------------------------------
__device__ __forceinline__ int nanhit(unsigned u) {
    return (((u & 0x7F80u) == 0x7F80u) | (((u >> 16) & 0x7F80u) == 0x7F80u));
}
__global__ __launch_bounds__(256) void detect_kernel(const uint4* __restrict__ q,
                                                     int* __restrict__ flag) {
    __shared__ int s;
    if (threadIdx.x == 0) s = 0;
    __syncthreads();
    int hit = 0;
#pragma unroll
    for (int r = 0; r < 8; ++r) {
        uint4 v = q[threadIdx.x + 256 * r];
        hit |= nanhit(v.x) | nanhit(v.y) | nanhit(v.z) | nanhit(v.w);
    }
    if (__any(hit)) { if ((threadIdx.x & 63) == 0) atomicOr(&s, 1); }
    __syncthreads();
    if (threadIdx.x == 0) flag[0] = s;
}

__device__ __forceinline__ float ldf(const void* X, size_t i, int f32) {
    return f32 ? ((const float*)X)[i] : __bfloat162float(((const __hip_bfloat16*)X)[i]);
}

// ---------------------------------------------------------------------------
// Megaprep (one dispatch): q convert (4096 blocks), Wq^T (256), Wc^T (256),
// Wkv^T (32), kvred build (1536): kvred rows 0..511 = sum of 8 chunks of kv,
// 512..1023 = first chunk, 1024..1535 = last chunk (all bf16).
// ---------------------------------------------------------------------------
__global__ __launch_bounds__(256) void megaprep(const void* __restrict__ q,
                                                const void* __restrict__ kv,
                                                const void* __restrict__ Wq,
                                                const void* __restrict__ Wkv,
                                                const void* __restrict__ Wc,
                                                __hip_bfloat16* __restrict__ qbuf,
                                                __hip_bfloat16* __restrict__ WqT,
                                                __hip_bfloat16* __restrict__ WkvT,
                                                __hip_bfloat16* __restrict__ WcT,
                                                __hip_bfloat16* __restrict__ kvred,
                                                const int* __restrict__ flag) {
    __shared__ float t[64][65];
    const int b = blockIdx.x;
    const int f32 = flag[0];
    const int tid = threadIdx.x;

    if (b < 4096) {
        // convert q -> bf16
        int i = (b * 256 + tid) * 4;
        if (f32) {
            float4 v = *(const float4*)((const float*)q + i);
            __hip_bfloat162 tmp[2] = {__float22bfloat162_rn({v.x, v.y}),
                                      __float22bfloat162_rn({v.z, v.w})};
            *(short4*)((short*)qbuf + i) = *(const short4*)tmp;
        } else {
            *(short4*)((short*)qbuf + i) = *(const short4*)((const short*)q + i);
        }
    } else if (b < 4640) {
        // weight transposes
        const void* W;
        __hip_bfloat16* WT;
        int K = 1024, N, n0, k0;
        if (b < 4352) {
            int bx = b - 4096; W = Wq; WT = WqT; N = 1024;
            n0 = (bx & 15) * 64; k0 = (bx >> 4) * 64;
        } else if (b < 4608) {
            int bx = b - 4352; W = Wc; WT = WcT; N = 1024;
            n0 = (bx & 15) * 64; k0 = (bx >> 4) * 64;
        } else {
            int bx = b - 4608; W = Wkv; WT = WkvT; N = 128;
            n0 = (bx & 1) * 64; k0 = (bx >> 1) * 64;
        }
        const int tx = tid & 63;
        const int ty = tid >> 6;
#pragma unroll
        for (int r = 0; r < 16; ++r) {
            int k = ty + r * 4;
            t[k][tx] = ldf(W, (size_t)(k0 + k) * N + n0 + tx, f32);
        }
        __syncthreads();
#pragma unroll
        for (int r = 0; r < 16; ++r) {
            int n = ty + r * 4;
            WT[(size_t)(n0 + n) * K + k0 + tx] = __float2bfloat16(t[tx][n]);
        }
    } else {
        // kvred row build
        int y2 = b - 4640;          // 0..1535
        int c = tid * 4;
        float a0 = 0.f, a1 = 0.f, a2 = 0.f, a3 = 0.f;
        if (y2 < 512) {
#pragma unroll
            for (int z = 0; z < C_; ++z) {
                size_t base = (size_t)(z * W_ + y2) * 1024 + c;
                a0 += ldf(kv, base + 0, f32);
                a1 += ldf(kv, base + 1, f32);
                a2 += ldf(kv, base + 2, f32);
                a3 += ldf(kv, base + 3, f32);
            }
        } else {
            int row = (y2 < 1024) ? (y2 - 512) : (3584 + y2 - 1024);
            size_t base = (size_t)row * 1024 + c;
            a0 = ldf(kv, base + 0, f32);
            a1 = ldf(kv, base + 1, f32);
            a2 = ldf(kv, base + 2, f32);
            a3 = ldf(kv, base + 3, f32);
        }
        __hip_bfloat162 tmp[2] = {__float22bfloat162_rn({a0, a1}),
                                  __float22bfloat162_rn({a2, a3})};
        *(short4*)((short*)kvred + (size_t)y2 * 1024 + c) = *(const short4*)tmp;
    }
}

// ---------------------------------------------------------------------------
// MFMA GEMM: C[M,N] = alpha * A[M,K] @ BT[N,K]^T, bf16 in, fp32 accum.
// 128x64 tile, BK=64 (two BK=32 sub-tiles). plain=0: XCD swizzle mapping.
// cMode: 0 = follow flag (fp32 if flag else bf16), 1 = fp32, 2 = bf16
// ---------------------------------------------------------------------------
__global__ __launch_bounds__(256) void gemm_bt_mfma(const __hip_bfloat16* __restrict__ A,
                                                    const __hip_bfloat16* __restrict__ BT,
                                                    void* __restrict__ C,
                                                    int M, int N, int K, float alpha,
                                                    int cMode, int ntiles, int plain,
                                                    const int* __restrict__ flag) {
    __shared__ __hip_bfloat16 Asl[2][128 * 32];
    __shared__ __hip_bfloat16 Bsl[2][64 * 32];

    const int bid = blockIdx.x;
    int mt, nt;
    if (plain) { mt = bid / ntiles; nt = bid % ntiles; }
    else {
        int g = bid / (8 * ntiles);
        int rem = bid % (8 * ntiles);
        mt = g * 8 + (rem & 7);
        nt = rem >> 3;
    }
    const int m0 = mt * 128;
    const int n0 = nt * 64;

    const int tid = threadIdx.x;
    const int lane = tid & 63;
    const int wv = tid >> 6;
    const int wm = wv >> 1;
    const int wn = wv & 1;
    const int col = lane & 15;
    const int quad = lane >> 4;

    const int srow = lane >> 2;
    const int scol = (lane & 3) * 8;
    const __hip_bfloat16* Ag = A + (size_t)m0 * K;
    const __hip_bfloat16* Bg = BT + (size_t)n0 * K;

    f32x4 acc[4][2] = {};

    for (int k0 = 0; k0 < K; k0 += 64) {
#pragma unroll
        for (int h = 0; h < 2; ++h) {
            int arow = wv * 32 + h * 16 + srow;
#pragma unroll
            for (int kc = 0; kc < 2; ++kc)
                async16(Ag + (size_t)arow * K + k0 + kc * 32 + scol,
                        &Asl[kc][arow * 32 + scol]);
        }
        {
            int brow = wv * 16 + srow;
#pragma unroll
            for (int kc = 0; kc < 2; ++kc)
                async16(Bg + (size_t)brow * K + k0 + kc * 32 + scol,
                        &Bsl[kc][brow * 32 + scol]);
        }
        __syncthreads();

#pragma unroll
        for (int kc = 0; kc < 2; ++kc) {
            short8 af[4], bfr[2];
#pragma unroll
            for (int i = 0; i < 4; ++i)
                af[i] = *(const short8*)(&Asl[kc][(wm * 64 + i * 16 + col) * 32 + quad * 8]);
#pragma unroll
            for (int j = 0; j < 2; ++j)
                bfr[j] = *(const short8*)(&Bsl[kc][(wn * 32 + j * 16 + col) * 32 + quad * 8]);
#pragma unroll
            for (int am = 0; am < 4; ++am)
#pragma unroll
                for (int bn = 0; bn < 2; ++bn)
                    acc[am][bn] = __builtin_amdgcn_mfma_f32_16x16x32_bf16(af[am], bfr[bn], acc[am][bn], 0, 0, 0);
        }
        __syncthreads();
    }

    int cF = (cMode == 1) ? 1 : ((cMode == 2) ? 0 : flag[0]);
#pragma unroll
    for (int am = 0; am < 4; ++am)
#pragma unroll
        for (int bn = 0; bn < 2; ++bn)
#pragma unroll
            for (int r = 0; r < 4; ++r) {
                size_t ci = (size_t)(m0 + wm * 64 + am * 16 + quad * 4 + r) * N
                            + n0 + wn * 32 + bn * 16 + col;
                float v = acc[am][bn][r] * alpha;
                if (cF) ((float*)C)[ci] = v;
                else ((__hip_bfloat16*)C)[ci] = __float2bfloat16(v);
            }
}

// ---------------------------------------------------------------------------
// Combine kvp_red [1536][128] fp32 -> bf16 Kb [1536][64] (natural order) and
// Vt [64][1536] with PV-operand key permutation: within each 32-key chunk,
// pos = 8*((w&15)>>2) + 4*(w>>4) + (w&3).
// kvp_red rows: y = sum-all, 512+y = first chunk, 1024+y = last chunk.
// ---------------------------------------------------------------------------
__global__ __launch_bounds__(256) void sums_kernel(const float* __restrict__ kvp_red,
                                                   __hip_bfloat16* __restrict__ Kb,
                                                   __hip_bfloat16* __restrict__ Vt) {
    int t = blockIdx.x * 256 + threadIdx.x;
    int d = t & 63;
    int y = t >> 6;

    float kc = kvp_red[(size_t)y * 128 + d];
    float kf = kvp_red[(size_t)(512 + y) * 128 + d];
    float kl = kvp_red[(size_t)(1024 + y) * 128 + d];
    float vc = kvp_red[(size_t)y * 128 + 64 + d];
    float vf = kvp_red[(size_t)(512 + y) * 128 + 64 + d];
    float vl = kvp_red[(size_t)(1024 + y) * 128 + 64 + d];

    float kvals[3] = {kc - kl, kc, kc - kf};
    float vvals[3] = {vc - vl, vc, vc - vf};
#pragma unroll
    for (int e = 0; e < 3; ++e) {
        int key = e * W_ + y;
        Kb[(size_t)key * 64 + d] = __float2bfloat16(kvals[e]);
        int w = key & 31;
        int pos = (key & ~31) + 8 * ((w & 15) >> 2) + 4 * (w >> 4) + (w & 3);
        Vt[(size_t)d * W3_ + pos] = __float2bfloat16(vvals[e]);
    }
}

// ---------------------------------------------------------------------------
// Flash MFMA attention, register-only P path (operand-swap trick):
//   S^T = mfma(A=Kfrag, B=Qfrag)  -> lane holds P[qrow=col][key=16g+4q+r]
//   pack two 16-key groups per lane -> PV A-operand directly (keys permuted
//   to match, absorbed into Vt's stored permutation). No LDS in main loop.
// Block = 64 rows, 4 waves key-split (384 keys each). LDS epilogue only.
// ---------------------------------------------------------------------------
#define LSROW 66
__global__ __launch_bounds__(256, 3) void attn_kernel(const __hip_bfloat16* __restrict__ qb,
                                                      const __hip_bfloat16* __restrict__ Kb,
                                                      const __hip_bfloat16* __restrict__ Vt,
                                                      __hip_bfloat16* __restrict__ ctx) {
    __shared__ float Ls[4][16 * LSROW];   // 16896 B
    __shared__ float lsum[4][64];         // 1024 B

    const int tid = threadIdx.x;
    const int lane = tid & 63;
    const int wv = tid >> 6;
    const int m0 = blockIdx.x * 64;
    const int col = lane & 15;
    const int quad = lane >> 4;

    f32x4 O[4][4] = {};        // [rg][f]; lane holds O[qrow=4q+r][d=16f+col]
    float lrow[4] = {};        // per-rg scalar: qrow = col

    for (int t = 0; t < 6; ++t) {
        const int kt = wv * 384 + t * 64;

        // K frags: 4 groups x 2 d-chunks
        short8 kb0[4], kb1[4];
#pragma unroll
        for (int g = 0; g < 4; ++g) {
            const __hip_bfloat16* kp = Kb + (size_t)(kt + g * 16 + col) * 64 + quad * 8;
            kb0[g] = *(const short8*)(kp);
            kb1[g] = *(const short8*)(kp + 32);
        }

        // QK^T (swapped operands) + exp2 + in-register pack to PV A-frags
        short8 ap[4][2];
#pragma unroll
        for (int rg = 0; rg < 4; ++rg) {
            const __hip_bfloat16* qp = qb + (size_t)(m0 + rg * 16 + col) * 64 + quad * 8;
            short8 q0 = *(const short8*)(qp);
            short8 q1 = *(const short8*)(qp + 32);
            f32x4 St[4];
#pragma unroll
            for (int g = 0; g < 4; ++g) {
                f32x4 s = {};
                s = __builtin_amdgcn_mfma_f32_16x16x32_bf16(kb0[g], q0, s, 0, 0, 0);
                s = __builtin_amdgcn_mfma_f32_16x16x32_bf16(kb1[g], q1, s, 0, 0, 0);
                St[g] = s;
            }
#pragma unroll
            for (int g = 0; g < 4; ++g)
#pragma unroll
                for (int r = 0; r < 4; ++r) St[g][r] = FEXP2(St[g][r]);
            lrow[rg] += (St[0][0] + St[0][1] + St[0][2] + St[0][3])
                      + (St[1][0] + St[1][1] + St[1][2] + St[1][3])
                      + (St[2][0] + St[2][1] + St[2][2] + St[2][3])
                      + (St[3][0] + St[3][1] + St[3][2] + St[3][3]);
#pragma unroll
            for (int p = 0; p < 2; ++p) {
                __hip_bfloat162 tmp[4] = {
                    __float22bfloat162_rn({St[2 * p][0], St[2 * p][1]}),
                    __float22bfloat162_rn({St[2 * p][2], St[2 * p][3]}),
                    __float22bfloat162_rn({St[2 * p + 1][0], St[2 * p + 1][1]}),
                    __float22bfloat162_rn({St[2 * p + 1][2], St[2 * p + 1][3]})};
                ap[rg][p] = *(const short8*)tmp;
            }
        }

        // PV: per 32-key pair, V B-frags then MFMA into O
#pragma unroll
        for (int p = 0; p < 2; ++p) {
            short8 vb[4];
#pragma unroll
            for (int f = 0; f < 4; ++f)
                vb[f] = *(const short8*)(Vt + (size_t)(f * 16 + col) * W3_ + kt + p * 32 + quad * 8);
#pragma unroll
            for (int rg = 0; rg < 4; ++rg)
#pragma unroll
                for (int f = 0; f < 4; ++f)
                    O[rg][f] = __builtin_amdgcn_mfma_f32_16x16x32_bf16(ap[rg][p], vb[f], O[rg][f], 0, 0, 0);
        }
    }

    // reduce lrow over quad lanes (same col = same qrow)
#pragma unroll
    for (int rg = 0; rg < 4; ++rg) {
        lrow[rg] += __shfl_xor(lrow[rg], 16, 64);
        lrow[rg] += __shfl_xor(lrow[rg], 32, 64);
    }
    if (quad == 0) {
#pragma unroll
        for (int rg = 0; rg < 4; ++rg) lsum[wv][rg * 16 + col] = lrow[rg];
    }

    // epilogue: 4 phases of 16 rows; cross-wave O sum + normalize + store
#pragma unroll
    for (int rg = 0; rg < 4; ++rg) {
#pragma unroll
        for (int f = 0; f < 4; ++f)
#pragma unroll
            for (int r = 0; r < 4; ++r)
                Ls[wv][(quad * 4 + r) * LSROW + f * 16 + col] = O[rg][f][r];
        __syncthreads();
        {
            int row = tid >> 4;
            int c0 = (tid & 15) * 4;
            float ltot = lsum[0][rg * 16 + row] + lsum[1][rg * 16 + row]
                       + lsum[2][rg * 16 + row] + lsum[3][rg * 16 + row];
            float inv = 1.f / ltot;
            __hip_bfloat162 tmp[2];
            float v[4];
#pragma unroll
            for (int j = 0; j < 4; ++j)
                v[j] = (Ls[0][row * LSROW + c0 + j] + Ls[1][row * LSROW + c0 + j]
                      + Ls[2][row * LSROW + c0 + j] + Ls[3][row * LSROW + c0 + j]) * inv;
            tmp[0] = __float22bfloat162_rn({v[0], v[1]});
            tmp[1] = __float22bfloat162_rn({v[2], v[3]});
            *(short4*)(ctx + (size_t)(m0 + rg * 16 + row) * 64 + c0) = *(const short4*)tmp;
        }
        __syncthreads();
    }
}

// ---------------------------------------------------------------------------
// Launch
// ---------------------------------------------------------------------------
extern "C" void kernel_launch(void* const* d_in, const int* in_sizes, int n_in,
                              void* d_out, int out_size, void* d_ws, size_t ws_size,
                              hipStream_t stream) {
    const void* q   = d_in[0];
    const void* kv  = d_in[1];
    const void* Wq  = d_in[2];
    const void* Wkv = d_in[3];
    const void* Wc  = d_in[4];

    char* ws = (char*)d_ws;
    size_t off = 0;
    int* flag = (int*)(ws + off); off += 1024;
    __hip_bfloat16* qbuf   = (__hip_bfloat16*)(ws + off); off += (size_t)L_ * DM_ * 2;     // 8 MB
    __hip_bfloat16* WqT    = (__hip_bfloat16*)(ws + off); off += (size_t)DM_ * DM_ * 2;    // 2 MB
    __hip_bfloat16* WkvT   = (__hip_bfloat16*)(ws + off); off += (size_t)128 * DM_ * 2;    // 256 KB
    __hip_bfloat16* WcT    = (__hip_bfloat16*)(ws + off); off += (size_t)DM_ * DM_ * 2;    // 2 MB
    __hip_bfloat16* qb     = (__hip_bfloat16*)(ws + off); off += (size_t)L_ * DM_ * 2;     // 8 MB
    __hip_bfloat16* kvred  = (__hip_bfloat16*)(ws + off); off += (size_t)1536 * 1024 * 2;  // 3 MB
    float*          kvpred = (float*)(ws + off);          off += (size_t)1536 * 128 * 4;   // 768 KB
    __hip_bfloat16* Kb     = (__hip_bfloat16*)(ws + off); off += (size_t)W3_ * 64 * 2;     // 192 KB
    __hip_bfloat16* Vt     = (__hip_bfloat16*)(ws + off); off += (size_t)64 * W3_ * 2;     // 192 KB
    __hip_bfloat16* ctxb   = (__hip_bfloat16*)(ws + off);                                  // 8 MB

    detect_kernel<<<1, 256, 0, stream>>>((const uint4*)q, flag);

    // one prep dispatch: q convert + 3 weight transposes + kvred build
    megaprep<<<6176, 256, 0, stream>>>(q, kv, Wq, Wkv, Wc,
                                       qbuf, WqT, WkvT, WcT, kvred, flag);

    // qb = (q @ Wq) * (1/8)*log2(e), bf16 (exp2-domain logits)
    gemm_bt_mfma<<<512, 256, 0, stream>>>(qbuf, WqT, qb, L_, DM_, DM_,
                                          0.125f * 1.44269504f, 2, 16, 0, flag);
    // kvp_red = kvred @ Wkv, fp32  (M=1536 after chunk-sum commutation)
    gemm_bt_mfma<<<24, 256, 0, stream>>>(kvred, WkvT, kvpred, 1536, 128, DM_,
                                         1.0f, 1, 2, 1, flag);
    sums_kernel<<<128, 256, 0, stream>>>(kvpred, Kb, Vt);
    attn_kernel<<<dim3(NROWS_ / 64), 256, 0, stream>>>(qb, Kb, Vt, ctxb);
    // out = ctx @ Wc, dtype per flag
    gemm_bt_mfma<<<512, 256, 0, stream>>>(ctxb, WcT, d_out, L_, DM_, DM_,
                                          1.0f, 0, 16, 0, flag);
}